// Round 6
// baseline (530.894 us; speedup 1.0000x reference)
//
#include <hip/hip_runtime.h>

#define BB 512
#define SS 1024
#define TT 64

__device__ __forceinline__ float wsum64(float v) {
#pragma unroll
  for (int off = 32; off > 0; off >>= 1) v += __shfl_xor(v, off, 64);
  return v;
}

// X-macro list: apply M(i) for i = 0..63
#define E_LIST(M) \
  M(0) M(1) M(2) M(3) M(4) M(5) M(6) M(7) \
  M(8) M(9) M(10) M(11) M(12) M(13) M(14) M(15) \
  M(16) M(17) M(18) M(19) M(20) M(21) M(22) M(23) \
  M(24) M(25) M(26) M(27) M(28) M(29) M(30) M(31) \
  M(32) M(33) M(34) M(35) M(36) M(37) M(38) M(39) \
  M(40) M(41) M(42) M(43) M(44) M(45) M(46) M(47) \
  M(48) M(49) M(50) M(51) M(52) M(53) M(54) M(55) \
  M(56) M(57) M(58) M(59) M(60) M(61) M(62) M(63)

#define RLF(v, i) __int_as_float(__builtin_amdgcn_readlane(__float_as_int(v), (i)))

// Broadcast of lane i's p to all 64 lanes via the LDS crossbar (no LDS
// storage touched, no SGPR involved): every lane pulls src from lane
// (index>>2); index = zoff + 4*i is lane-uniform. zoff is an opaque zero
// VGPR so the +4*i constant folds into the DS offset field (no per-op VALU).
// Unlike v_readlane (VALU pipe, SGPR dest, VALU->SGPR hazards), this issues
// to the LDS pipe and pipelines under counted lgkmcnt waits.
#define BP(i) __builtin_amdgcn_ds_bpermute(zoff + 4 * (i), pb_)

// Banked issue/consume: load 8 broadcasts into one bank while the other
// bank's 8 FMAs consume — in-order DS returns match in-order consumption.
#define LDB8(B, j0, j1, j2, j3, j4, j5, j6, j7) \
  B##0 = BP(j0);                                \
  B##1 = BP(j1);                                \
  B##2 = BP(j2);                                \
  B##3 = BP(j3);                                \
  B##4 = BP(j4);                                \
  B##5 = BP(j5);                                \
  B##6 = BP(j6);                                \
  B##7 = BP(j7);

// FMA order i ascending, accumulator = i&3 — identical to the verified
// round-0 kernel => bitwise-identical sums.
#define FM8(B, i0, i1, i2, i3, i4, i5, i6, i7) \
  a0 = fmaf(__int_as_float(B##0), E##i0, a0);  \
  a1 = fmaf(__int_as_float(B##1), E##i1, a1);  \
  a2 = fmaf(__int_as_float(B##2), E##i2, a2);  \
  a3 = fmaf(__int_as_float(B##3), E##i3, a3);  \
  a0 = fmaf(__int_as_float(B##4), E##i4, a0);  \
  a1 = fmaf(__int_as_float(B##5), E##i5, a1);  \
  a2 = fmaf(__int_as_float(B##6), E##i6, a2);  \
  a3 = fmaf(__int_as_float(B##7), E##i7, a3);

#define FMA_ALL_BP                       \
  int t0, t1, t2, t3, t4, t5, t6, t7;    \
  int u0, u1, u2, u3, u4, u5, u6, u7;    \
  LDB8(t, 0, 1, 2, 3, 4, 5, 6, 7)        \
  LDB8(u, 8, 9, 10, 11, 12, 13, 14, 15)  \
  FM8(t, 0, 1, 2, 3, 4, 5, 6, 7)         \
  LDB8(t, 16, 17, 18, 19, 20, 21, 22, 23)\
  FM8(u, 8, 9, 10, 11, 12, 13, 14, 15)   \
  LDB8(u, 24, 25, 26, 27, 28, 29, 30, 31)\
  FM8(t, 16, 17, 18, 19, 20, 21, 22, 23) \
  LDB8(t, 32, 33, 34, 35, 36, 37, 38, 39)\
  FM8(u, 24, 25, 26, 27, 28, 29, 30, 31) \
  LDB8(u, 40, 41, 42, 43, 44, 45, 46, 47)\
  FM8(t, 32, 33, 34, 35, 36, 37, 38, 39) \
  LDB8(t, 48, 49, 50, 51, 52, 53, 54, 55)\
  FM8(u, 40, 41, 42, 43, 44, 45, 46, 47) \
  LDB8(u, 56, 57, 58, 59, 60, 61, 62, 63)\
  FM8(t, 48, 49, 50, 51, 52, 53, 54, 55) \
  FM8(u, 56, 57, 58, 59, 60, 61, 62, 63)

// One recurrence step, linear domain, delayed scalar normalization.
// fwd (DIR=0): broadcast p; s_j = sum_i p_i E_ij ; p' = s * (f_j * inv)
// bwd (DIR=1): broadcast t_j = p_j * f_j * inv ; p'_i = sum_j E_ij t_j
// inv = 1/readfirstlane(s) from the PREVIOUS step (off critical path).
#define CRF_STEP(ev, mkv)                                                           \
  do {                                                                              \
    float f_ = __expf((ev) * (mkv));                                                \
    float pv_ = (DIR == 1) ? p * (f_ * inv) : p;                                    \
    int pb_ = __float_as_int(pv_);                                                  \
    float a0 = 0.f, a1 = 0.f, a2 = 0.f, a3 = 0.f;                                   \
    FMA_ALL_BP                                                                      \
    float s_ = (a0 + a1) + (a2 + a3);                                               \
    p = (DIR == 0) ? s_ * (f_ * inv) : s_;                                          \
    float rn_ = __int_as_float(__builtin_amdgcn_readfirstlane(__float_as_int(s_))); \
    inv = __builtin_amdgcn_rcpf(rn_);                                               \
    float lg_ = __logf(rn_);                                                        \
    Lacc += lg_;                                                                    \
    lastlg = lg_;                                                                   \
  } while (0)

template <int DIR>
__device__ __forceinline__ void part_run(int b, int lane, const float* __restrict__ em,
                                         const float* __restrict__ mask,
                                         const float* __restrict__ trans,
                                         float* __restrict__ outv) {
  // Opaque zero VGPR: base register for the bpermute index so each +4*i
  // folds into the DS offset immediate instead of 64 hoisted constants.
  int zoff;
  asm("v_mov_b32 %0, 0" : "=v"(zoff));

  // Per-lane E fragment as 64 NAMED scalars (never an array -> never scratch).
  // fwd lane j holds column E[i][j]; bwd lane i holds row E[i][j].
  const float* tp = trans + (DIR == 0 ? lane : lane * TT);
#define EINIT(i) float E##i = __expf((DIR == 0) ? tp[(i)*TT] : tp[(i)]);
  E_LIST(EINIT)
#undef EINIT

  const float* emb = em + (size_t)b * SS * TT;
  const float* mkb = mask + (size_t)b * SS;

  constexpr int NST = (DIR == 0) ? (SS / 2 - 1) : (SS / 2);  // 511 fwd, 512 bwd
  constexpr int S0 = (DIR == 0) ? 1 : (SS - 1);
  constexpr int SD = (DIR == 0) ? 1 : -1;
  constexpr int NG8 = NST / 8;    // full groups of 8 steps
  constexpr int TAIL8 = NST & 7;  // 7 fwd, 0 bwd

  float p = (DIR == 0) ? __expf(emb[lane] * mkb[0]) : 1.0f;
  float inv = 1.0f, Lacc = 0.0f, lastlg = 0.0f;

  // 8-deep emission prefetch (coalesced: lane j reads em[b][s][j])
  float ebuf[8];
#pragma unroll
  for (int k = 0; k < 8; ++k) ebuf[k] = emb[(S0 + SD * k) * TT + lane];
  const float* ep = emb + (ptrdiff_t)(S0 + SD * 8) * TT + lane;

  // mask: one coalesced vector load per 64-step window, prefetched ONE WINDOW
  // (64 steps) ahead so the load is never consumed in the same iteration.
  float mv = mkb[S0 + SD * lane];  // window 0
  float mvn = 0.f;
  for (int t8 = 0; t8 < NG8; ++t8) {
    if ((t8 & 7) == 0 && t8 != 0) mv = mvn;  // enter window t8>>3
    if ((t8 & 7) == 5)                       // prefetch window (t8>>3)+1
      mvn = mkb[S0 + SD * (((t8 >> 3) + 1) * 64 + lane)];
    const int base = (t8 & 7) * 8;
#pragma unroll
    for (int k = 0; k < 8; ++k) {
      float e = ebuf[k];
      ebuf[k] = *ep;  // prefetch step t+8; always in-bounds (fwd s<=519, bwd s>=504)
      ep += SD * TT;
      float mk = RLF(mv, base + k);
      CRF_STEP(e, mk);
    }
  }
  if constexpr (TAIL8 > 0) {  // fwd only: steps 504..510, window 7
#pragma unroll
    for (int k = 0; k < TAIL8; ++k) {
      float e = ebuf[k];
      float mk = RLF(mv, (NG8 & 7) * 8 + k);
      CRF_STEP(e, mk);
    }
  }

  outv[b * TT + lane] = __logf(p) + (Lacc - lastlg);
}

// Fused: blocks [0, 1024) = partition fwd/bwd; blocks [1024, 3072) = gold score
__global__ void __launch_bounds__(64, 1)
    fused_kernel(const float* __restrict__ em, const int* __restrict__ tags,
                 const float* __restrict__ mask, const float* __restrict__ trans,
                 float* __restrict__ alpha, float* __restrict__ beta,
                 float* __restrict__ gpart) {
  const int lane = threadIdx.x;
  const int bid = blockIdx.x;
  if (bid < 2 * BB) {
    const int b = bid >> 1;
    if ((bid & 1) == 0)
      part_run<0>(b, lane, em, mask, trans, alpha);
    else
      part_run<1>(b, lane, em, mask, trans, beta);
  } else {
    const int gid = bid - 2 * BB;  // 0..2047
    const int b = gid >> 2, q = gid & 3;
    const int* tg = tags + b * SS;
    const float* mkb = mask + (size_t)b * SS;
    const float* emb = em + (size_t)b * SS * TT;
    float part = 0.f;
#pragma unroll
    for (int i = 0; i < 4; ++i) {
      int s = q * 256 + i * 64 + lane;
      int t1 = tg[s];
      float e = emb[s * TT + t1];
      float contrib = (s == 0) ? e : (trans[t1 * TT + tg[s - 1]] + e);
      part = fmaf(contrib, mkb[s], part);
    }
    part = wsum64(part);
    if (lane == 0) gpart[gid] = part;
  }
}

// Single block, 512 threads: thread b computes Z_b - gold_b, block-reduces, writes mean.
__global__ void combine_kernel(const float* __restrict__ alpha, const float* __restrict__ beta,
                               const float* __restrict__ gpart, float* __restrict__ out) {
  const int b = threadIdx.x;  // 0..511
  const float* av = alpha + b * TT;
  const float* bv = beta + b * TT;
  float m = -3.4e38f, s = 0.f;
#pragma unroll 8
  for (int j = 0; j < TT; ++j) {
    float v = av[j] + bv[j];
    float nm = fmaxf(m, v);
    s = s * __expf(m - nm) + __expf(v - nm);
    m = nm;
  }
  float Z = m + __logf(s);
  float g = gpart[4 * b] + gpart[4 * b + 1] + gpart[4 * b + 2] + gpart[4 * b + 3];
  float val = Z - g;
  val = wsum64(val);
  __shared__ float red[8];
  if ((threadIdx.x & 63) == 0) red[threadIdx.x >> 6] = val;
  __syncthreads();
  if (threadIdx.x == 0) {
    float t = 0.f;
#pragma unroll
    for (int w = 0; w < 8; ++w) t += red[w];
    out[0] = t * (1.0f / (float)BB);
  }
}

extern "C" void kernel_launch(void* const* d_in, const int* in_sizes, int n_in,
                              void* d_out, int out_size, void* d_ws, size_t ws_size,
                              hipStream_t stream) {
  const float* em = (const float*)d_in[0];
  const int* tags = (const int*)d_in[1];
  const float* mask = (const float*)d_in[2];
  const float* trans = (const float*)d_in[3];
  float* out = (float*)d_out;

  float* alpha = (float*)d_ws;      // 512*64
  float* beta = alpha + BB * TT;    // 512*64
  float* gpart = beta + BB * TT;    // 2048

  fused_kernel<<<2 * BB + 4 * BB, TT, 0, stream>>>(em, tags, mask, trans, alpha, beta, gpart);
  combine_kernel<<<1, BB, 0, stream>>>(alpha, beta, gpart, out);
}

// Round 8
// 341.751 us; speedup vs baseline: 1.5535x; 1.5535x over previous
//
#include <hip/hip_runtime.h>

#define BB 512
#define SS 1024
#define TT 64

typedef _Float16 h2 __attribute__((ext_vector_type(2)));

#if __has_builtin(__builtin_amdgcn_fdot2)
#define FDOT2(a, b, c) __builtin_amdgcn_fdot2((a), (b), (c), false)
#else
#define FDOT2(a, b, c) ((c) + (float)(a).x * (float)(b).x + (float)(a).y * (float)(b).y)
#endif

__device__ __forceinline__ float wsum64(float v) {
#pragma unroll
  for (int off = 32; off > 0; off >>= 1) v += __shfl_xor(v, off, 64);
  return v;
}

// X-macro list: apply M(q) for q = 0..31 (pair index over the 64-dim state)
#define H_LIST(M) \
  M(0) M(1) M(2) M(3) M(4) M(5) M(6) M(7) \
  M(8) M(9) M(10) M(11) M(12) M(13) M(14) M(15) \
  M(16) M(17) M(18) M(19) M(20) M(21) M(22) M(23) \
  M(24) M(25) M(26) M(27) M(28) M(29) M(30) M(31)

#define RLF(v, i) __int_as_float(__builtin_amdgcn_readlane(__float_as_int(v), (i)))

// One pair-term of the 64-term dot product:
// broadcast lane 2q's packed (w_2q, w_2q+1) f16x2, then one v_dot2_f32_f16
// (2 MACs, f32 accumulate). Accumulator = q&3, q ascending.
#define DOTQ(q)                                                          \
  {                                                                      \
    int r_ = __builtin_amdgcn_readlane(pkb_, 2 * (q));                   \
    acc_[(q)&3] = FDOT2(__builtin_bit_cast(h2, r_), Ep##q, acc_[(q)&3]); \
  }

// One recurrence step, linear domain, broadcast-side normalization.
// fwd (DIR=0): w_i = p_i * inv ; s_j = sum_i w_i E_ij ; p' = s * f_j
// bwd (DIR=1): w_j = p_j * f_j * inv ; s_i = sum_j E_ij w_j ; p' = s
// inv = rcp(readfirstlane(s)) from the PREVIOUS step. Telescoping gives the
// same final formula as the verified kernel: out = log(p) + (Lacc - lastlg).
// w is packed to f16 pairs for broadcast: pair partner fetched via DPP
// quad_perm lane^1 (VALU, no DS pipe), packed with v_cvt_pkrtz_f16_f32.
// fminf clamp guards the f16 range (65504) against rare ratio*f spikes.
#define CRF_STEP(ev, mkv)                                                           \
  do {                                                                              \
    float f_ = __expf((ev) * (mkv));                                                \
    float w_ = (DIR == 1) ? p * (f_ * inv) : p * inv;                               \
    w_ = fminf(w_, 60000.0f);                                                       \
    int nb_ = __builtin_amdgcn_update_dpp(0, __float_as_int(w_), 0xB1, 0xF, 0xF, true); \
    h2 pk_ = __builtin_bit_cast(h2, __builtin_amdgcn_cvt_pkrtz(w_, __int_as_float(nb_))); \
    int pkb_ = __builtin_bit_cast(int, pk_);                                        \
    float acc_[4] = {0.f, 0.f, 0.f, 0.f};                                           \
    H_LIST(DOTQ)                                                                    \
    float s_ = (acc_[0] + acc_[1]) + (acc_[2] + acc_[3]);                           \
    p = (DIR == 0) ? s_ * f_ : s_;                                                  \
    float rn_ = __int_as_float(__builtin_amdgcn_readfirstlane(__float_as_int(s_))); \
    inv = __builtin_amdgcn_rcpf(rn_);                                               \
    float lg_ = __logf(rn_);                                                        \
    Lacc += lg_;                                                                    \
    lastlg = lg_;                                                                   \
  } while (0)

template <int DIR>
__device__ __forceinline__ void part_run(int b, int lane, const float* __restrict__ em,
                                         const float* __restrict__ mask,
                                         const float* __restrict__ trans,
                                         float* __restrict__ outv) {
  // Per-lane E fragment as 32 NAMED f16x2 pairs (exp applied, RTN convert).
  // fwd lane j holds column E[i][j] paired over i; bwd lane i holds row
  // E[i][j] paired over j.
  const float* tp = trans + (DIR == 0 ? lane : lane * TT);
#define EINIT(q)                                                                   \
  h2 Ep##q = {                                                                     \
      (_Float16)__expf((DIR == 0) ? tp[(2 * (q)) * TT] : tp[2 * (q)]),             \
      (_Float16)__expf((DIR == 0) ? tp[(2 * (q) + 1) * TT] : tp[2 * (q) + 1])};
  H_LIST(EINIT)
#undef EINIT

  const float* emb = em + (size_t)b * SS * TT;
  const float* mkb = mask + (size_t)b * SS;

  constexpr int NST = (DIR == 0) ? (SS / 2 - 1) : (SS / 2);  // 511 fwd, 512 bwd
  constexpr int S0 = (DIR == 0) ? 1 : (SS - 1);
  constexpr int SD = (DIR == 0) ? 1 : -1;
  constexpr int NG8 = NST / 8;    // full groups of 8 steps
  constexpr int TAIL8 = NST & 7;  // 7 fwd, 0 bwd

  float p = (DIR == 0) ? __expf(emb[lane] * mkb[0]) : 1.0f;
  float inv = 1.0f, Lacc = 0.0f, lastlg = 0.0f;

  // 8-deep emission prefetch (coalesced: lane j reads em[b][s][j])
  float ebuf[8];
#pragma unroll
  for (int k = 0; k < 8; ++k) ebuf[k] = emb[(S0 + SD * k) * TT + lane];
  const float* ep = emb + (ptrdiff_t)(S0 + SD * 8) * TT + lane;

  // mask: one coalesced vector load per 64-step window, prefetched ONE WINDOW
  // (64 steps) ahead so the load is never consumed in the same iteration.
  float mv = mkb[S0 + SD * lane];  // window 0
  float mvn = 0.f;
  for (int t8 = 0; t8 < NG8; ++t8) {
    if ((t8 & 7) == 0 && t8 != 0) mv = mvn;  // enter window t8>>3
    if ((t8 & 7) == 5)                       // prefetch window (t8>>3)+1
      mvn = mkb[S0 + SD * (((t8 >> 3) + 1) * 64 + lane)];
    const int base = (t8 & 7) * 8;
#pragma unroll
    for (int k = 0; k < 8; ++k) {
      float e = ebuf[k];
      ebuf[k] = *ep;  // prefetch step t+8; always in-bounds (fwd s<=519, bwd s>=504)
      ep += SD * TT;
      float mk = RLF(mv, base + k);
      CRF_STEP(e, mk);
    }
  }
  if constexpr (TAIL8 > 0) {  // fwd only: steps 504..510, window 7
#pragma unroll
    for (int k = 0; k < TAIL8; ++k) {
      float e = ebuf[k];
      float mk = RLF(mv, (NG8 & 7) * 8 + k);
      CRF_STEP(e, mk);
    }
  }

  outv[b * TT + lane] = __logf(p) + (Lacc - lastlg);
}

// Fused: blocks [0, 1024) = partition fwd/bwd; blocks [1024, 3072) = gold score
__global__ void __launch_bounds__(64, 1)
    fused_kernel(const float* __restrict__ em, const int* __restrict__ tags,
                 const float* __restrict__ mask, const float* __restrict__ trans,
                 float* __restrict__ alpha, float* __restrict__ beta,
                 float* __restrict__ gpart) {
  const int lane = threadIdx.x;
  const int bid = blockIdx.x;
  if (bid < 2 * BB) {
    const int b = bid >> 1;
    if ((bid & 1) == 0)
      part_run<0>(b, lane, em, mask, trans, alpha);
    else
      part_run<1>(b, lane, em, mask, trans, beta);
  } else {
    const int gid = bid - 2 * BB;  // 0..2047
    const int b = gid >> 2, q = gid & 3;
    const int* tg = tags + b * SS;
    const float* mkb = mask + (size_t)b * SS;
    const float* emb = em + (size_t)b * SS * TT;
    float part = 0.f;
#pragma unroll
    for (int i = 0; i < 4; ++i) {
      int s = q * 256 + i * 64 + lane;
      int t1 = tg[s];
      float e = emb[s * TT + t1];
      float contrib = (s == 0) ? e : (trans[t1 * TT + tg[s - 1]] + e);
      part = fmaf(contrib, mkb[s], part);
    }
    part = wsum64(part);
    if (lane == 0) gpart[gid] = part;
  }
}

// Single block, 512 threads: thread b computes Z_b - gold_b, block-reduces, writes mean.
__global__ void combine_kernel(const float* __restrict__ alpha, const float* __restrict__ beta,
                               const float* __restrict__ gpart, float* __restrict__ out) {
  const int b = threadIdx.x;  // 0..511
  const float* av = alpha + b * TT;
  const float* bv = beta + b * TT;
  float m = -3.4e38f, s = 0.f;
#pragma unroll 8
  for (int j = 0; j < TT; ++j) {
    float v = av[j] + bv[j];
    float nm = fmaxf(m, v);
    s = s * __expf(m - nm) + __expf(v - nm);
    m = nm;
  }
  float Z = m + __logf(s);
  float g = gpart[4 * b] + gpart[4 * b + 1] + gpart[4 * b + 2] + gpart[4 * b + 3];
  float val = Z - g;
  val = wsum64(val);
  __shared__ float red[8];
  if ((threadIdx.x & 63) == 0) red[threadIdx.x >> 6] = val;
  __syncthreads();
  if (threadIdx.x == 0) {
    float t = 0.f;
#pragma unroll
    for (int w = 0; w < 8; ++w) t += red[w];
    out[0] = t * (1.0f / (float)BB);
  }
}

extern "C" void kernel_launch(void* const* d_in, const int* in_sizes, int n_in,
                              void* d_out, int out_size, void* d_ws, size_t ws_size,
                              hipStream_t stream) {
  const float* em = (const float*)d_in[0];
  const int* tags = (const int*)d_in[1];
  const float* mask = (const float*)d_in[2];
  const float* trans = (const float*)d_in[3];
  float* out = (float*)d_out;

  float* alpha = (float*)d_ws;      // 512*64
  float* beta = alpha + BB * TT;    // 512*64
  float* gpart = beta + BB * TT;    // 2048

  fused_kernel<<<2 * BB + 4 * BB, TT, 0, stream>>>(em, tags, mask, trans, alpha, beta, gpart);
  combine_kernel<<<1, BB, 0, stream>>>(alpha, beta, gpart, out);
}